// Round 20
// baseline (2108.597 us; speedup 1.0000x reference)
//
#include <hip/hip_runtime.h>
#include <stdint.h>

// FP8 SwiGLU MLP. Round 19 kernel (resubmit — infra failure): R18 + T14
// async-split for the X/A tiles: global->REG loads issued at step top (hidden
// under compute), ds_write to LDS at step tail (after end-barrier; next
// start-barrier's lgkmcnt(0) drains). G/U (and B) keep the dbuf gld_lds path
// with vmcnt(12). 2D supertile (R15). MX fp8 MFMA K=128, unit scales.
//
// Shapes: B*S = M = 8192, H = 4096, I = 11008.

typedef float f32x4 __attribute__((ext_vector_type(4)));
typedef int   i32x4 __attribute__((ext_vector_type(4)));
typedef int   i32x8 __attribute__((ext_vector_type(8)));
typedef unsigned int u32;

#define AS1 __attribute__((address_space(1)))
#define AS3 __attribute__((address_space(3)))

#define TM 128
#define TN 128
#define BKB 128   // K-bytes per step (one MX K=128 step)

#define SCALE1 0x7F7F7F7F  // e8m0 = 127 -> 2^0 in every byte

__device__ __forceinline__ void gld_lds16(const uint8_t* g, uint8_t* l) {
  __builtin_amdgcn_global_load_lds((const AS1 u32*)g, (AS3 u32*)l, 16, 0, 0);
}

__device__ __forceinline__ uint8_t f32_to_fp8(float v) {
  v = fminf(fmaxf(v, -448.f), 448.f);
  int r = __builtin_amdgcn_cvt_pk_fp8_f32(v, v, 0, false);
  return (uint8_t)(r & 0xff);
}

// read one lane's 32-byte K-chunk (two swizzled 16B halves) as v8i32
__device__ __forceinline__ i32x8 read_frag32(const uint8_t* s, int row, int ko, int swz) {
  const uint8_t* p = s + row * BKB;
  i32x4 lo = *(const i32x4*)(p + ((ko) ^ swz));
  i32x4 hi = *(const i32x4*)(p + ((ko + 16) ^ swz));
  return __builtin_shufflevector(lo, hi, 0, 1, 2, 3, 4, 5, 6, 7);
}

// ---------------- quantize f32 -> fp8 bytes (8 elems/thread) ----------------
__global__ __launch_bounds__(256) void quant_fp8_k(const float* __restrict__ in,
                                                   uint8_t* __restrict__ out,
                                                   const float* __restrict__ scale_ptr,
                                                   long n8) {
  long i = (long)blockIdx.x * 256 + threadIdx.x;
  if (i >= n8) return;
  float inv = scale_ptr ? (1.0f / scale_ptr[0]) : 1.0f;
  const float4* p = (const float4*)(in + i * 8);
  float4 a = p[0], b = p[1];
  float v0 = fminf(fmaxf(a.x * inv, -448.f), 448.f);
  float v1 = fminf(fmaxf(a.y * inv, -448.f), 448.f);
  float v2 = fminf(fmaxf(a.z * inv, -448.f), 448.f);
  float v3 = fminf(fmaxf(a.w * inv, -448.f), 448.f);
  float v4 = fminf(fmaxf(b.x * inv, -448.f), 448.f);
  float v5 = fminf(fmaxf(b.y * inv, -448.f), 448.f);
  float v6 = fminf(fmaxf(b.z * inv, -448.f), 448.f);
  float v7 = fminf(fmaxf(b.w * inv, -448.f), 448.f);
  int lo = __builtin_amdgcn_cvt_pk_fp8_f32(v0, v1, 0, false);
  lo = __builtin_amdgcn_cvt_pk_fp8_f32(v2, v3, lo, true);
  int hi = __builtin_amdgcn_cvt_pk_fp8_f32(v4, v5, 0, false);
  hi = __builtin_amdgcn_cvt_pk_fp8_f32(v6, v7, hi, true);
  ((int2*)out)[i] = make_int2(lo, hi);
}

// ---------------- fused dual GEMM1 + SwiGLU + fp8 requant ----------------
__global__ __launch_bounds__(256, 2) void gemm1_swiglu(
    const uint8_t* __restrict__ Xq,   // [M][H]
    const uint8_t* __restrict__ Gq,   // [I][H]
    const uint8_t* __restrict__ Uq,   // [I][H]
    uint8_t* __restrict__ Hq,         // [M][I]
    const float* __restrict__ gws, const float* __restrict__ uws,
    const float* __restrict__ gis, const float* __restrict__ uis,
    const float* __restrict__ dis,
    int M, int H, int I) {
  __shared__ uint8_t sX[TM * BKB];        // 16KB, single-buffered (reg-fed)
  __shared__ uint8_t sG[2][TN * BKB];     // 2 x 16KB
  __shared__ uint8_t sU[2][TN * BKB];     // 2 x 16KB  -> 80KB

  const int tid = threadIdx.x;
  const int wave = tid >> 6, lane = tid & 63;
  const int wr = wave >> 1, wc = wave & 1;      // 2x2 wave grid, 64x64 each
  const int lrow = lane & 15;
  const int lkg = lane >> 4;
  const int swz = (lrow & 7) << 4;
  const int ko = lkg * 32;

  // 2D supertile (R15): GX=43 x GY=16 groups, y fastest.
  const int GX = 43, GY = 16;
  const int per = GX * GY;                    // 688
  const int g = blockIdx.x / per, w = blockIdx.x % per;
  const int ggx = g & 1, ggy = g >> 1;
  const int xb = ggx * GX + w / GY;
  const int yb = ggy * GY + (w % GY);
  const int bM = yb * TM, bN = xb * TN;

  f32x4 accG[4][4] = {};
  f32x4 accU[4][4] = {};

  const uint8_t* gx = Xq + (size_t)bM * H;
  const uint8_t* gg = Gq + (size_t)bN * H;
  const uint8_t* gu = Uq + (size_t)bN * H;

  int4 xr0, xr1, xr2, xr3;                    // X tile in regs (T14)
  auto loadXreg = [&](int k0) {
#pragma unroll
    for (int it = 0; it < 4; ++it) {
      int c = it * 256 + tid;
      int r = c >> 3;
      int col = ((c & 7) ^ (r & 7)) * 16;     // pre-swizzled source
      const int4 v = *(const int4*)(gx + (size_t)r * H + k0 + col);
      if (it == 0) xr0 = v; else if (it == 1) xr1 = v;
      else if (it == 2) xr2 = v; else xr3 = v;
    }
  };
  auto writeXlds = [&]() {
    *(int4*)(sX + (0 * 4 + wave) * 1024 + lane * 16) = xr0;
    *(int4*)(sX + (1 * 4 + wave) * 1024 + lane * 16) = xr1;
    *(int4*)(sX + (2 * 4 + wave) * 1024 + lane * 16) = xr2;
    *(int4*)(sX + (3 * 4 + wave) * 1024 + lane * 16) = xr3;
  };
  auto stageGU = [&](int buf, int k0) {       // 8 gld_lds issues/thread
#pragma unroll
    for (int it = 0; it < 4; ++it) {
      int c = it * 256 + tid;
      int r = c >> 3;
      int col = ((c & 7) ^ (r & 7)) * 16;
      size_t go = (size_t)r * H + k0 + col;
      int lo = (it * 4 + wave) * 1024;
      gld_lds16(gg + go, &sG[buf][lo]);
      gld_lds16(gu + go, &sU[buf][lo]);
    }
  };

  const int NK = H / BKB;                     // 32

  // prologue: X(0) regs -> LDS; GU(0) in flight
  loadXreg(0);
  stageGU(0, 0);
  writeXlds();                                // compiler waits Xr automatically

  for (int t = 0; t < NK; ++t) {
    const int cur = t & 1, nxt = cur ^ 1;
    const bool pre = (t + 1 < NK);
    if (pre) {
      loadXreg((t + 1) * BKB);                // issue early; hidden by compute
      stageGU(nxt, (t + 1) * BKB);            // dbuf prefetch, in flight
      asm volatile("s_waitcnt vmcnt(12)" ::: "memory");  // retires GU(t)
    } else {
      asm volatile("s_waitcnt vmcnt(0)" ::: "memory");
    }
    // drain this wave's ds_writes of X(t) (and all LDS ops) before sync
    asm volatile("s_waitcnt lgkmcnt(0)" ::: "memory");
    __builtin_amdgcn_s_barrier();             // raw barrier: no implicit drain

    i32x8 af[4];
#pragma unroll
    for (int i = 0; i < 4; ++i)
      af[i] = read_frag32(sX, wr * 64 + i * 16 + lrow, ko, swz);
#pragma unroll
    for (int j = 0; j < 4; ++j) {
      i32x8 gf = read_frag32(&sG[cur][0], wc * 64 + j * 16 + lrow, ko, swz);
      i32x8 uf = read_frag32(&sU[cur][0], wc * 64 + j * 16 + lrow, ko, swz);
#pragma unroll
      for (int i = 0; i < 4; ++i) {
        accG[i][j] = __builtin_amdgcn_mfma_scale_f32_16x16x128_f8f6f4(
            af[i], gf, accG[i][j], 0, 0, 0, SCALE1, 0, SCALE1);
        accU[i][j] = __builtin_amdgcn_mfma_scale_f32_16x16x128_f8f6f4(
            af[i], uf, accU[i][j], 0, 0, 0, SCALE1, 0, SCALE1);
      }
    }
    asm volatile("s_waitcnt lgkmcnt(0)" ::: "memory");   // reads of sX/sGU done
    __builtin_amdgcn_s_barrier();             // end of step: sX free to rewrite
    if (pre) writeXlds();                     // X(t+1) regs -> sX (auto vmcnt)
  }

  const float sg = gws[0] * gis[0];
  const float su = uws[0] * uis[0];
  const float invd = 1.0f / dis[0];

  uint8_t* sH = sX;                // reuse 16KB as output staging (linear)

#pragma unroll
  for (int i = 0; i < 4; ++i)
#pragma unroll
    for (int j = 0; j < 4; ++j)
#pragma unroll
      for (int t = 0; t < 4; ++t) {
        float g2 = accG[i][j][t] * sg;
        float u = accU[i][j][t] * su;
        float h = (g2 / (1.0f + expf(-g2))) * u * invd;
        int row = wr * 64 + i * 16 + lkg * 4 + t;   // C: col=lane&15, row=(lane>>4)*4+t
        int col = wc * 64 + j * 16 + lrow;
        sH[row * TN + col] = f32_to_fp8(h);
      }
  __syncthreads();
#pragma unroll
  for (int it = 0; it < 4; ++it) {
    int o = (it * 256 + tid) * 16;
    int row = o >> 7, col = o & 127;
    *(int4*)(Hq + (size_t)(bM + row) * I + bN + col) = *(const int4*)(sH + o);
  }
}

// ---------------- GEMM2: dual B-panel (TN=256), A reg-staged, B dbuf ----------------
__global__ __launch_bounds__(256, 2) void gemm2_down(
    const uint8_t* __restrict__ Hq,   // [M][I]
    const uint8_t* __restrict__ Dq,   // [Hd][I]
    float* __restrict__ Out,          // [M][Hd]
    const float* __restrict__ dws, const float* __restrict__ dis,
    int M, int I, int Hd) {
  __shared__ uint8_t sA[TM * BKB];          // 16KB, single-buffered (reg-fed)
  __shared__ uint8_t sB[2][2 * TN * BKB];   // 2 x 32KB -> 80KB total

  const int tid = threadIdx.x;
  const int wave = tid >> 6, lane = tid & 63;
  const int wr = wave >> 1, wc = wave & 1;   // wave-tile: 64 rows x 128 cols
  const int lrow = lane & 15;
  const int lkg = lane >> 4;
  const int swz = (lrow & 7) << 4;
  const int ko = lkg * 32;

  // 2D supertile (R15): GX=16 covers ALL x-panels, GY=16 -> 256-block groups.
  const int g = blockIdx.x >> 8, w = blockIdx.x & 255;   // 4 groups
  const int xb = w >> 4;
  const int yb = (g << 4) + (w & 15);
  const int bM = yb * TM, bN = xb * 256;

  f32x4 acc[4][8] = {};

  const uint8_t* ga = Hq + (size_t)bM * I;
  const uint8_t* gb = Dq + (size_t)bN * I;

  int4 ar0, ar1, ar2, ar3;
  auto loadAreg = [&](int k0) {
#pragma unroll
    for (int it = 0; it < 4; ++it) {
      int c = it * 256 + tid;
      int r = c >> 3;
      int col = ((c & 7) ^ (r & 7)) * 16;
      const int4 v = *(const int4*)(ga + (size_t)r * I + k0 + col);
      if (it == 0) ar0 = v; else if (it == 1) ar1 = v;
      else if (it == 2) ar2 = v; else ar3 = v;
    }
  };
  auto writeAlds = [&]() {
    *(int4*)(sA + (0 * 4 + wave) * 1024 + lane * 16) = ar0;
    *(int4*)(sA + (1 * 4 + wave) * 1024 + lane * 16) = ar1;
    *(int4*)(sA + (2 * 4 + wave) * 1024 + lane * 16) = ar2;
    *(int4*)(sA + (3 * 4 + wave) * 1024 + lane * 16) = ar3;
  };
  auto stageB = [&](int buf, int k0) {       // 8 issues/thread
#pragma unroll
    for (int it = 0; it < 8; ++it) {
      int c = it * 256 + tid;
      int r = c >> 3;                        // 0..255
      int col = ((c & 7) ^ (r & 7)) * 16;
      gld_lds16(gb + (size_t)r * I + k0 + col, &sB[buf][(it * 4 + wave) * 1024]);
    }
  };

  const int NK = I / BKB;                    // 86

  loadAreg(0);
  stageB(0, 0);
  writeAlds();

  for (int t = 0; t < NK; ++t) {
    const int cur = t & 1, nxt = cur ^ 1;
    const bool pre = (t + 1 < NK);
    if (pre) {
      loadAreg((t + 1) * BKB);
      stageB(nxt, (t + 1) * BKB);
      asm volatile("s_waitcnt vmcnt(12)" ::: "memory");  // retires B(t)
    } else {
      asm volatile("s_waitcnt vmcnt(0)" ::: "memory");
    }
    asm volatile("s_waitcnt lgkmcnt(0)" ::: "memory");
    __builtin_amdgcn_s_barrier();

    i32x8 af[4];
#pragma unroll
    for (int i = 0; i < 4; ++i)
      af[i] = read_frag32(sA, wr * 64 + i * 16 + lrow, ko, swz);
#pragma unroll
    for (int j = 0; j < 8; ++j) {
      i32x8 bf = read_frag32(&sB[cur][0], wc * 128 + j * 16 + lrow, ko, swz);
#pragma unroll
      for (int i = 0; i < 4; ++i)
        acc[i][j] = __builtin_amdgcn_mfma_scale_f32_16x16x128_f8f6f4(
            af[i], bf, acc[i][j], 0, 0, 0, SCALE1, 0, SCALE1);
    }
    asm volatile("s_waitcnt lgkmcnt(0)" ::: "memory");
    __builtin_amdgcn_s_barrier();
    if (pre) writeAlds();
  }

  const float ds = dws[0] * dis[0];
#pragma unroll
  for (int i = 0; i < 4; ++i)
#pragma unroll
    for (int j = 0; j < 8; ++j) {
      int row = bM + wr * 64 + i * 16 + lkg * 4;
      int col = bN + wc * 128 + j * 16 + lrow;
#pragma unroll
      for (int t = 0; t < 4; ++t)
        Out[(size_t)(row + t) * Hd + col] = acc[i][j][t] * ds;
    }
}

extern "C" void kernel_launch(void* const* d_in, const int* in_sizes, int n_in,
                              void* d_out, int out_size, void* d_ws, size_t ws_size,
                              hipStream_t stream) {
  const float* x   = (const float*)d_in[0];
  const float* gw  = (const float*)d_in[1];
  const float* uw  = (const float*)d_in[2];
  const float* dw  = (const float*)d_in[3];
  const float* gws = (const float*)d_in[4];
  const float* uws = (const float*)d_in[5];
  const float* dws = (const float*)d_in[6];
  const float* gis = (const float*)d_in[7];
  const float* uis = (const float*)d_in[8];
  const float* dis = (const float*)d_in[9];

  const int Hd = 4096;
  const int M  = in_sizes[0] / Hd;          // 8192
  const int I  = in_sizes[1] / Hd;          // 11008

  const size_t szX = (size_t)M * Hd;        // 33.5 MB
  const size_t szW = (size_t)I * Hd;        // 45.1 MB
  const size_t szH = (size_t)M * I;         // 90.2 MB

  uint8_t* xq = (uint8_t*)d_ws;
  uint8_t* gq = xq + szX;
  uint8_t* uq = gq + szW;
  uint8_t* hq = uq + szW;
  uint8_t* dq = gq;                         // reuse gate slot after GEMM1

  if (ws_size < szX + 2 * szW + szH) return;  // fail loudly (out stays poisoned)

  float* out = (float*)d_out;

  // 1. quantize activations and GEMM1 weights
  {
    long n8 = (long)(szX / 8);
    quant_fp8_k<<<dim3((n8 + 255) / 256), dim3(256), 0, stream>>>(x, xq, gis, n8);
  }
  {
    long n8 = (long)(szW / 8);
    quant_fp8_k<<<dim3((n8 + 255) / 256), dim3(256), 0, stream>>>(gw, gq, nullptr, n8);
    quant_fp8_k<<<dim3((n8 + 255) / 256), dim3(256), 0, stream>>>(uw, uq, nullptr, n8);
  }

  // 2. fused gate/up GEMM + SwiGLU + fp8 requant of hidden
  gemm1_swiglu<<<dim3((I / TN) * (M / TM)), dim3(256), 0, stream>>>(
      xq, gq, uq, hq, gws, uws, gis, uis, dis, M, Hd, I);

  // 3. quantize down weights (into gate slot), then down GEMM
  {
    long n8 = (long)(szW / 8);
    quant_fp8_k<<<dim3((n8 + 255) / 256), dim3(256), 0, stream>>>(dw, dq, nullptr, n8);
  }
  gemm2_down<<<dim3((Hd / 256) * (M / TM)), dim3(256), 0, stream>>>(
      hq, dq, out, dws, dis, M, I, Hd);
}

// Round 24
// 1508.382 us; speedup vs baseline: 1.3979x; 1.3979x over previous
//
#include <hip/hip_runtime.h>
#include <stdint.h>

// FP8 SwiGLU MLP. Round 21 kernel (3rd resubmit — infra failures R21-R23):
// gemm1 rebuilt as a faithful m201-style phase schedule: BM=256 x BN=128,
// 512 thr / 8 waves, dbuf 128KB LDS, 4 phases/K-tile each {ds-reads || 2
// stage-issues, barrier, lgkmcnt(0), setprio+8 MFMA, barrier}, vmcnt(2) ONLY
// at phase 0 (never 0 in loop). No reg staging (R20 lesson: zero VGPR
// headroom -> spill). gemm2/quant = R18 (proven). 2D supertile raster.
// MX fp8 MFMA K=128, unit scales.
//
// Shapes: B*S = M = 8192, H = 4096, I = 11008.

typedef float f32x4 __attribute__((ext_vector_type(4)));
typedef int   i32x4 __attribute__((ext_vector_type(4)));
typedef int   i32x8 __attribute__((ext_vector_type(8)));
typedef unsigned int u32;

#define AS1 __attribute__((address_space(1)))
#define AS3 __attribute__((address_space(3)))

#define TM 128
#define TN 128
#define BM1 256
#define BN1 128
#define BKB 128   // K-bytes per step (one MX K=128 step)

#define SCALE1 0x7F7F7F7F  // e8m0 = 127 -> 2^0 in every byte

__device__ __forceinline__ void gld_lds16(const uint8_t* g, uint8_t* l) {
  __builtin_amdgcn_global_load_lds((const AS1 u32*)g, (AS3 u32*)l, 16, 0, 0);
}

__device__ __forceinline__ uint8_t f32_to_fp8(float v) {
  v = fminf(fmaxf(v, -448.f), 448.f);
  int r = __builtin_amdgcn_cvt_pk_fp8_f32(v, v, 0, false);
  return (uint8_t)(r & 0xff);
}

// read one lane's 32-byte K-chunk (two swizzled 16B halves) as v8i32
__device__ __forceinline__ i32x8 read_frag32(const uint8_t* s, int row, int ko, int swz) {
  const uint8_t* p = s + row * BKB;
  i32x4 lo = *(const i32x4*)(p + ((ko) ^ swz));
  i32x4 hi = *(const i32x4*)(p + ((ko + 16) ^ swz));
  return __builtin_shufflevector(lo, hi, 0, 1, 2, 3, 4, 5, 6, 7);
}

// ---------------- quantize f32 -> fp8 bytes (8 elems/thread) ----------------
__global__ __launch_bounds__(256) void quant_fp8_k(const float* __restrict__ in,
                                                   uint8_t* __restrict__ out,
                                                   const float* __restrict__ scale_ptr,
                                                   long n8) {
  long i = (long)blockIdx.x * 256 + threadIdx.x;
  if (i >= n8) return;
  float inv = scale_ptr ? (1.0f / scale_ptr[0]) : 1.0f;
  const float4* p = (const float4*)(in + i * 8);
  float4 a = p[0], b = p[1];
  float v0 = fminf(fmaxf(a.x * inv, -448.f), 448.f);
  float v1 = fminf(fmaxf(a.y * inv, -448.f), 448.f);
  float v2 = fminf(fmaxf(a.z * inv, -448.f), 448.f);
  float v3 = fminf(fmaxf(a.w * inv, -448.f), 448.f);
  float v4 = fminf(fmaxf(b.x * inv, -448.f), 448.f);
  float v5 = fminf(fmaxf(b.y * inv, -448.f), 448.f);
  float v6 = fminf(fmaxf(b.z * inv, -448.f), 448.f);
  float v7 = fminf(fmaxf(b.w * inv, -448.f), 448.f);
  int lo = __builtin_amdgcn_cvt_pk_fp8_f32(v0, v1, 0, false);
  lo = __builtin_amdgcn_cvt_pk_fp8_f32(v2, v3, lo, true);
  int hi = __builtin_amdgcn_cvt_pk_fp8_f32(v4, v5, 0, false);
  hi = __builtin_amdgcn_cvt_pk_fp8_f32(v6, v7, hi, true);
  ((int2*)out)[i] = make_int2(lo, hi);
}

// ---------------- fused dual GEMM1 + SwiGLU + fp8 requant (phase schedule) ----------------
__global__ __launch_bounds__(512, 2) void gemm1_swiglu(
    const uint8_t* __restrict__ Xq,   // [M][H]
    const uint8_t* __restrict__ Gq,   // [I][H]
    const uint8_t* __restrict__ Uq,   // [I][H]
    uint8_t* __restrict__ Hq,         // [M][I]
    const float* __restrict__ gws, const float* __restrict__ uws,
    const float* __restrict__ gis, const float* __restrict__ uis,
    const float* __restrict__ dis,
    int M, int H, int I) {
  __shared__ uint8_t sX[2][BM1 * BKB];   // 2 x 32KB
  __shared__ uint8_t sG[2][BN1 * BKB];   // 2 x 16KB
  __shared__ uint8_t sU[2][BN1 * BKB];   // 2 x 16KB  -> 128KB

  const int tid = threadIdx.x;
  const int wave = tid >> 6, lane = tid & 63;
  const int wr = wave >> 1, wc = wave & 1;      // 4x2 wave grid, 64x64 wave-tile
  const int lrow = lane & 15;
  const int lkg = lane >> 4;
  const int swz = (lrow & 7) << 4;
  const int ko = lkg * 32;

  // 2D supertile: GX=43 x GY=8 (2048 M-rows per group), y fastest.
  const int GX = 43, GY = 8;
  const int per = GX * GY;                    // 344; nwg = 2752 = 8 groups
  const int g = blockIdx.x / per, w = blockIdx.x % per;
  const int ggx = g & 1, ggy = g >> 1;        // 2 x-groups, 4 y-groups
  const int xb = ggx * GX + w / GY;           // 0..85
  const int yb = ggy * GY + (w % GY);         // 0..31
  const int bM = yb * BM1, bN = xb * BN1;

  f32x4 accG[4][4] = {};
  f32x4 accU[4][4] = {};

  const uint8_t* gx = Xq + (size_t)bM * H;
  const uint8_t* gg = Gq + (size_t)bN * H;
  const uint8_t* gu = Uq + (size_t)bN * H;

  auto stage_x = [&](int buf, int it, int k0) {
    int c = it * 512 + tid;
    int r = c >> 3;                            // 0..255
    int col = ((c & 7) ^ (r & 7)) * 16;        // pre-swizzled source
    gld_lds16(gx + (size_t)r * H + k0 + col, &sX[buf][(it * 8 + wave) * 1024]);
  };
  auto stage_g = [&](int buf, int it, int k0) {
    int c = it * 512 + tid;
    int r = c >> 3;                            // 0..127
    int col = ((c & 7) ^ (r & 7)) * 16;
    gld_lds16(gg + (size_t)r * H + k0 + col, &sG[buf][(it * 8 + wave) * 1024]);
  };
  auto stage_u = [&](int buf, int it, int k0) {
    int c = it * 512 + tid;
    int r = c >> 3;
    int col = ((c & 7) ^ (r & 7)) * 16;
    gld_lds16(gu + (size_t)r * H + k0 + col, &sU[buf][(it * 8 + wave) * 1024]);
  };

  const int NK = H / BKB;                      // 32

  // prologue: all 8 chunks of tile 0 -> buf 0
  stage_x(0, 0, 0); stage_x(0, 1, 0); stage_x(0, 2, 0); stage_x(0, 3, 0);
  stage_g(0, 0, 0); stage_g(0, 1, 0); stage_u(0, 0, 0); stage_u(0, 1, 0);

  for (int t = 0; t < NK; ++t) {
    const int cur = t & 1, nxt = cur ^ 1;
    const int k1 = (t + 1) * BKB;
    const bool pre = (t + 1 < NK);

    // ---- phase 0: arrival wait + af + j=0 quadrant ----
    if (pre) {
      stage_x(nxt, 0, k1); stage_g(nxt, 0, k1);            // 2 issues
      asm volatile("s_waitcnt vmcnt(2)" ::: "memory");     // tile t arrived
    } else {
      asm volatile("s_waitcnt vmcnt(0)" ::: "memory");
    }
    __builtin_amdgcn_s_barrier();            // publish: all waves' t-loads in LDS

    i32x8 af[4];
#pragma unroll
    for (int i = 0; i < 4; ++i)
      af[i] = read_frag32(&sX[cur][0], wr * 64 + i * 16 + lrow, ko, swz);
    {
      i32x8 gf = read_frag32(&sG[cur][0], wc * 64 + 0 * 16 + lrow, ko, swz);
      i32x8 uf = read_frag32(&sU[cur][0], wc * 64 + 0 * 16 + lrow, ko, swz);
      asm volatile("s_waitcnt lgkmcnt(0)" ::: "memory");
      __builtin_amdgcn_s_setprio(1);
#pragma unroll
      for (int i = 0; i < 4; ++i) {
        accG[i][0] = __builtin_amdgcn_mfma_scale_f32_16x16x128_f8f6f4(
            af[i], gf, accG[i][0], 0, 0, 0, SCALE1, 0, SCALE1);
        accU[i][0] = __builtin_amdgcn_mfma_scale_f32_16x16x128_f8f6f4(
            af[i], uf, accU[i][0], 0, 0, 0, SCALE1, 0, SCALE1);
      }
      __builtin_amdgcn_s_setprio(0);
    }
    __builtin_amdgcn_s_barrier();

    // ---- phases 1..3: j quadrant + 2 stage issues each ----
#pragma unroll
    for (int j = 1; j < 4; ++j) {
      i32x8 gf = read_frag32(&sG[cur][0], wc * 64 + j * 16 + lrow, ko, swz);
      i32x8 uf = read_frag32(&sU[cur][0], wc * 64 + j * 16 + lrow, ko, swz);
      if (pre) {
        if (j == 1)      { stage_x(nxt, 1, k1); stage_g(nxt, 1, k1); }
        else if (j == 2) { stage_x(nxt, 2, k1); stage_u(nxt, 0, k1); }
        else             { stage_x(nxt, 3, k1); stage_u(nxt, 1, k1); }
      }
      __builtin_amdgcn_s_barrier();
      asm volatile("s_waitcnt lgkmcnt(0)" ::: "memory");
      __builtin_amdgcn_s_setprio(1);
#pragma unroll
      for (int i = 0; i < 4; ++i) {
        accG[i][j] = __builtin_amdgcn_mfma_scale_f32_16x16x128_f8f6f4(
            af[i], gf, accG[i][j], 0, 0, 0, SCALE1, 0, SCALE1);
        accU[i][j] = __builtin_amdgcn_mfma_scale_f32_16x16x128_f8f6f4(
            af[i], uf, accU[i][j], 0, 0, 0, SCALE1, 0, SCALE1);
      }
      __builtin_amdgcn_s_setprio(0);
      __builtin_amdgcn_s_barrier();
    }
  }

  const float sg = gws[0] * gis[0];
  const float su = uws[0] * uis[0];
  const float invd = 1.0f / dis[0];

  uint8_t* sH = &sX[0][0];         // 32KB staging for the 256x128 fp8 out-tile

#pragma unroll
  for (int i = 0; i < 4; ++i)
#pragma unroll
    for (int j = 0; j < 4; ++j)
#pragma unroll
      for (int tt = 0; tt < 4; ++tt) {
        float g2 = accG[i][j][tt] * sg;
        float u = accU[i][j][tt] * su;
        float h = (g2 / (1.0f + expf(-g2))) * u * invd;
        int row = wr * 64 + i * 16 + lkg * 4 + tt;   // C: col=lane&15, row=(lane>>4)*4+tt
        int col = wc * 64 + j * 16 + lrow;
        sH[row * BN1 + col] = f32_to_fp8(h);
      }
  __syncthreads();
#pragma unroll
  for (int it = 0; it < 4; ++it) {
    int o = (it * 512 + tid) * 16;
    int row = o >> 7, col = o & 127;
    *(int4*)(Hq + (size_t)(bM + row) * I + bN + col) = *(const int4*)(sH + o);
  }
}

// ---------------- GEMM2 (R18): dual B-panel (TN=256) + B-dbuf counted vmcnt ----------------
__global__ __launch_bounds__(256, 2) void gemm2_down(
    const uint8_t* __restrict__ Hq,   // [M][I]
    const uint8_t* __restrict__ Dq,   // [Hd][I]
    float* __restrict__ Out,          // [M][Hd]
    const float* __restrict__ dws, const float* __restrict__ dis,
    int M, int I, int Hd) {
  __shared__ uint8_t sA[TM * BKB];          // 16KB, single-buffered
  __shared__ uint8_t sB[2][2 * TN * BKB];   // 2 x 32KB -> 80KB total

  const int tid = threadIdx.x;
  const int wave = tid >> 6, lane = tid & 63;
  const int wr = wave >> 1, wc = wave & 1;   // wave-tile: 64 rows x 128 cols
  const int lrow = lane & 15;
  const int lkg = lane >> 4;
  const int swz = (lrow & 7) << 4;
  const int ko = lkg * 32;

  // 2D supertile (R15): GX=16 covers ALL x-panels, GY=16 -> 256-block groups.
  const int g = blockIdx.x >> 8, w = blockIdx.x & 255;   // 4 groups
  const int xb = w >> 4;
  const int yb = (g << 4) + (w & 15);
  const int bM = yb * TM, bN = xb * 256;

  f32x4 acc[4][8] = {};

  const uint8_t* ga = Hq + (size_t)bM * I;
  const uint8_t* gb = Dq + (size_t)bN * I;

  auto stageA = [&](int k0) {                // 4 issues/thread
#pragma unroll
    for (int it = 0; it < 4; ++it) {
      int c = it * 256 + tid;
      int r = c >> 3;
      int col = ((c & 7) ^ (r & 7)) * 16;
      gld_lds16(ga + (size_t)r * I + k0 + col, sA + (it * 4 + wave) * 1024);
    }
  };
  auto stageB = [&](int buf, int k0) {       // 8 issues/thread
#pragma unroll
    for (int it = 0; it < 8; ++it) {
      int c = it * 256 + tid;
      int r = c >> 3;                        // 0..255
      int col = ((c & 7) ^ (r & 7)) * 16;
      gld_lds16(gb + (size_t)r * I + k0 + col, &sB[buf][(it * 4 + wave) * 1024]);
    }
  };

  const int NK = I / BKB;                    // 86
  stageB(0, 0);

  for (int t = 0; t < NK; ++t) {
    const int cur = t & 1, nxt = cur ^ 1;
    stageA(t * BKB);
    if (t + 1 < NK) {
      stageB(nxt, (t + 1) * BKB);
      asm volatile("s_waitcnt vmcnt(8)" ::: "memory");  // A(t)+B(t) arrived
    } else {
      asm volatile("s_waitcnt vmcnt(0)" ::: "memory");
    }
    __builtin_amdgcn_s_barrier();

    i32x8 af[4];
#pragma unroll
    for (int i = 0; i < 4; ++i)
      af[i] = read_frag32(sA, wr * 64 + i * 16 + lrow, ko, swz);
#pragma unroll
    for (int j = 0; j < 8; ++j) {
      i32x8 bf = read_frag32(&sB[cur][0], wc * 128 + j * 16 + lrow, ko, swz);
#pragma unroll
      for (int i = 0; i < 4; ++i)
        acc[i][j] = __builtin_amdgcn_mfma_scale_f32_16x16x128_f8f6f4(
            af[i], bf, acc[i][j], 0, 0, 0, SCALE1, 0, SCALE1);
    }
    asm volatile("s_waitcnt lgkmcnt(0)" ::: "memory");
    __builtin_amdgcn_s_barrier();
  }

  const float ds = dws[0] * dis[0];
#pragma unroll
  for (int i = 0; i < 4; ++i)
#pragma unroll
    for (int j = 0; j < 8; ++j) {
      int row = bM + wr * 64 + i * 16 + lkg * 4;
      int col = bN + wc * 128 + j * 16 + lrow;
#pragma unroll
      for (int t = 0; t < 4; ++t)
        Out[(size_t)(row + t) * Hd + col] = acc[i][j][t] * ds;
    }
}

extern "C" void kernel_launch(void* const* d_in, const int* in_sizes, int n_in,
                              void* d_out, int out_size, void* d_ws, size_t ws_size,
                              hipStream_t stream) {
  const float* x   = (const float*)d_in[0];
  const float* gw  = (const float*)d_in[1];
  const float* uw  = (const float*)d_in[2];
  const float* dw  = (const float*)d_in[3];
  const float* gws = (const float*)d_in[4];
  const float* uws = (const float*)d_in[5];
  const float* dws = (const float*)d_in[6];
  const float* gis = (const float*)d_in[7];
  const float* uis = (const float*)d_in[8];
  const float* dis = (const float*)d_in[9];

  const int Hd = 4096;
  const int M  = in_sizes[0] / Hd;          // 8192
  const int I  = in_sizes[1] / Hd;          // 11008

  const size_t szX = (size_t)M * Hd;        // 33.5 MB
  const size_t szW = (size_t)I * Hd;        // 45.1 MB
  const size_t szH = (size_t)M * I;         // 90.2 MB

  uint8_t* xq = (uint8_t*)d_ws;
  uint8_t* gq = xq + szX;
  uint8_t* uq = gq + szW;
  uint8_t* hq = uq + szW;
  uint8_t* dq = gq;                         // reuse gate slot after GEMM1

  if (ws_size < szX + 2 * szW + szH) return;  // fail loudly (out stays poisoned)

  float* out = (float*)d_out;

  // 1. quantize activations and GEMM1 weights
  {
    long n8 = (long)(szX / 8);
    quant_fp8_k<<<dim3((n8 + 255) / 256), dim3(256), 0, stream>>>(x, xq, gis, n8);
  }
  {
    long n8 = (long)(szW / 8);
    quant_fp8_k<<<dim3((n8 + 255) / 256), dim3(256), 0, stream>>>(gw, gq, nullptr, n8);
    quant_fp8_k<<<dim3((n8 + 255) / 256), dim3(256), 0, stream>>>(uw, uq, nullptr, n8);
  }

  // 2. fused gate/up GEMM + SwiGLU + fp8 requant of hidden
  gemm1_swiglu<<<dim3((I / BN1) * (M / BM1)), dim3(512), 0, stream>>>(
      xq, gq, uq, hq, gws, uws, gis, uis, dis, M, Hd, I);

  // 3. quantize down weights (into gate slot), then down GEMM
  {
    long n8 = (long)(szW / 8);
    quant_fp8_k<<<dim3((n8 + 255) / 256), dim3(256), 0, stream>>>(dw, dq, nullptr, n8);
  }
  gemm2_down<<<dim3((Hd / 256) * (M / TM)), dim3(256), 0, stream>>>(
      hq, dq, out, dws, dis, M, I, Hd);
}

// Round 25
// 1170.438 us; speedup vs baseline: 1.8015x; 1.2887x over previous
//
#include <hip/hip_runtime.h>
#include <stdint.h>

// FP8 SwiGLU MLP. FINAL (R18 restore — session best, 1177us): R15 supertile
// base + partial double-buffer with counted vmcnt, sized to KEEP 2 blocks/CU
// (R9/R13/R17/R21 lesson: co-residency is the dominant overlap mechanism;
// every 1-block/CU schedule lost). gemm1: X single (16KB) + G/U dbuf (2x32KB)
// = 80KB = 160/2. Per K-step: issue X(t), issue G/U(t+1), vmcnt(8) ->
// G/U(t+1) stays in flight across compute; raw s_barrier. gemm2 same pattern
// (A single, B dbuf). 2D supertile raster. MX fp8 MFMA K=128, unit scales,
// T2 swizzled staging.
//
// Shapes: B*S = M = 8192, H = 4096, I = 11008.

typedef float f32x4 __attribute__((ext_vector_type(4)));
typedef int   i32x4 __attribute__((ext_vector_type(4)));
typedef int   i32x8 __attribute__((ext_vector_type(8)));
typedef unsigned int u32;

#define AS1 __attribute__((address_space(1)))
#define AS3 __attribute__((address_space(3)))

#define TM 128
#define TN 128
#define BKB 128   // K-bytes per step (one MX K=128 step)

#define SCALE1 0x7F7F7F7F  // e8m0 = 127 -> 2^0 in every byte

__device__ __forceinline__ void gld_lds16(const uint8_t* g, uint8_t* l) {
  __builtin_amdgcn_global_load_lds((const AS1 u32*)g, (AS3 u32*)l, 16, 0, 0);
}

__device__ __forceinline__ uint8_t f32_to_fp8(float v) {
  v = fminf(fmaxf(v, -448.f), 448.f);
  int r = __builtin_amdgcn_cvt_pk_fp8_f32(v, v, 0, false);
  return (uint8_t)(r & 0xff);
}

// read one lane's 32-byte K-chunk (two swizzled 16B halves) as v8i32
__device__ __forceinline__ i32x8 read_frag32(const uint8_t* s, int row, int ko, int swz) {
  const uint8_t* p = s + row * BKB;
  i32x4 lo = *(const i32x4*)(p + ((ko) ^ swz));
  i32x4 hi = *(const i32x4*)(p + ((ko + 16) ^ swz));
  return __builtin_shufflevector(lo, hi, 0, 1, 2, 3, 4, 5, 6, 7);
}

// ---------------- quantize f32 -> fp8 bytes (8 elems/thread) ----------------
__global__ __launch_bounds__(256) void quant_fp8_k(const float* __restrict__ in,
                                                   uint8_t* __restrict__ out,
                                                   const float* __restrict__ scale_ptr,
                                                   long n8) {
  long i = (long)blockIdx.x * 256 + threadIdx.x;
  if (i >= n8) return;
  float inv = scale_ptr ? (1.0f / scale_ptr[0]) : 1.0f;
  const float4* p = (const float4*)(in + i * 8);
  float4 a = p[0], b = p[1];
  float v0 = fminf(fmaxf(a.x * inv, -448.f), 448.f);
  float v1 = fminf(fmaxf(a.y * inv, -448.f), 448.f);
  float v2 = fminf(fmaxf(a.z * inv, -448.f), 448.f);
  float v3 = fminf(fmaxf(a.w * inv, -448.f), 448.f);
  float v4 = fminf(fmaxf(b.x * inv, -448.f), 448.f);
  float v5 = fminf(fmaxf(b.y * inv, -448.f), 448.f);
  float v6 = fminf(fmaxf(b.z * inv, -448.f), 448.f);
  float v7 = fminf(fmaxf(b.w * inv, -448.f), 448.f);
  int lo = __builtin_amdgcn_cvt_pk_fp8_f32(v0, v1, 0, false);
  lo = __builtin_amdgcn_cvt_pk_fp8_f32(v2, v3, lo, true);
  int hi = __builtin_amdgcn_cvt_pk_fp8_f32(v4, v5, 0, false);
  hi = __builtin_amdgcn_cvt_pk_fp8_f32(v6, v7, hi, true);
  ((int2*)out)[i] = make_int2(lo, hi);
}

// ---------------- fused dual GEMM1 + SwiGLU + fp8 requant ----------------
__global__ __launch_bounds__(256, 2) void gemm1_swiglu(
    const uint8_t* __restrict__ Xq,   // [M][H]
    const uint8_t* __restrict__ Gq,   // [I][H]
    const uint8_t* __restrict__ Uq,   // [I][H]
    uint8_t* __restrict__ Hq,         // [M][I]
    const float* __restrict__ gws, const float* __restrict__ uws,
    const float* __restrict__ gis, const float* __restrict__ uis,
    const float* __restrict__ dis,
    int M, int H, int I) {
  __shared__ uint8_t sX[TM * BKB];        // 16KB, single-buffered
  __shared__ uint8_t sG[2][TN * BKB];     // 2 x 16KB
  __shared__ uint8_t sU[2][TN * BKB];     // 2 x 16KB  -> 80KB = 160/2

  const int tid = threadIdx.x;
  const int wave = tid >> 6, lane = tid & 63;
  const int wr = wave >> 1, wc = wave & 1;      // 2x2 wave grid, 64x64 each
  const int lrow = lane & 15;
  const int lkg = lane >> 4;
  const int swz = (lrow & 7) << 4;
  const int ko = lkg * 32;

  // 2D supertile (R15): GX=43 x GY=16 groups, y fastest.
  const int GX = 43, GY = 16;
  const int per = GX * GY;                    // 688
  const int g = blockIdx.x / per, w = blockIdx.x % per;
  const int ggx = g & 1, ggy = g >> 1;
  const int xb = ggx * GX + w / GY;
  const int yb = ggy * GY + (w % GY);
  const int bM = yb * TM, bN = xb * TN;

  f32x4 accG[4][4] = {};
  f32x4 accU[4][4] = {};

  const uint8_t* gx = Xq + (size_t)bM * H;
  const uint8_t* gg = Gq + (size_t)bN * H;
  const uint8_t* gu = Uq + (size_t)bN * H;

  auto stageX = [&](int k0) {                 // 4 issues/thread
#pragma unroll
    for (int it = 0; it < 4; ++it) {
      int c = it * 256 + tid;
      int r = c >> 3;
      int col = ((c & 7) ^ (r & 7)) * 16;     // pre-swizzled source
      gld_lds16(gx + (size_t)r * H + k0 + col, sX + (it * 4 + wave) * 1024);
    }
  };
  auto stageGU = [&](int buf, int k0) {       // 8 issues/thread
#pragma unroll
    for (int it = 0; it < 4; ++it) {
      int c = it * 256 + tid;
      int r = c >> 3;
      int col = ((c & 7) ^ (r & 7)) * 16;
      size_t go = (size_t)r * H + k0 + col;
      int lo = (it * 4 + wave) * 1024;
      gld_lds16(gg + go, &sG[buf][lo]);
      gld_lds16(gu + go, &sU[buf][lo]);
    }
  };

  const int NK = H / BKB;                     // 32
  stageGU(0, 0);                              // prologue: G/U tile 0

  for (int t = 0; t < NK; ++t) {
    const int cur = t & 1, nxt = cur ^ 1;
    stageX(t * BKB);                          // sX free since end-barrier t-1
    if (t + 1 < NK) {
      stageGU(nxt, (t + 1) * BKB);            // prefetch; stays in flight
      asm volatile("s_waitcnt vmcnt(8)" ::: "memory");  // X(t)+G/U(t) arrived
    } else {
      asm volatile("s_waitcnt vmcnt(0)" ::: "memory");
    }
    __builtin_amdgcn_s_barrier();             // raw barrier: no implicit drain

    i32x8 af[4];
#pragma unroll
    for (int i = 0; i < 4; ++i)
      af[i] = read_frag32(sX, wr * 64 + i * 16 + lrow, ko, swz);
#pragma unroll
    for (int j = 0; j < 4; ++j) {
      i32x8 gf = read_frag32(&sG[cur][0], wc * 64 + j * 16 + lrow, ko, swz);
      i32x8 uf = read_frag32(&sU[cur][0], wc * 64 + j * 16 + lrow, ko, swz);
#pragma unroll
      for (int i = 0; i < 4; ++i) {
        accG[i][j] = __builtin_amdgcn_mfma_scale_f32_16x16x128_f8f6f4(
            af[i], gf, accG[i][j], 0, 0, 0, SCALE1, 0, SCALE1);
        accU[i][j] = __builtin_amdgcn_mfma_scale_f32_16x16x128_f8f6f4(
            af[i], uf, accU[i][j], 0, 0, 0, SCALE1, 0, SCALE1);
      }
    }
    // this wave's LDS reads done; close the step so writes of t+1 can't race
    asm volatile("s_waitcnt lgkmcnt(0)" ::: "memory");
    __builtin_amdgcn_s_barrier();
  }

  const float sg = gws[0] * gis[0];
  const float su = uws[0] * uis[0];
  const float invd = 1.0f / dis[0];

  uint8_t* sH = sX;                // reuse 16KB as output staging (linear)

#pragma unroll
  for (int i = 0; i < 4; ++i)
#pragma unroll
    for (int j = 0; j < 4; ++j)
#pragma unroll
      for (int t = 0; t < 4; ++t) {
        float g2 = accG[i][j][t] * sg;
        float u = accU[i][j][t] * su;
        float h = (g2 / (1.0f + expf(-g2))) * u * invd;
        int row = wr * 64 + i * 16 + lkg * 4 + t;   // C: col=lane&15, row=(lane>>4)*4+t
        int col = wc * 64 + j * 16 + lrow;
        sH[row * TN + col] = f32_to_fp8(h);
      }
  __syncthreads();
#pragma unroll
  for (int it = 0; it < 4; ++it) {
    int o = (it * 256 + tid) * 16;
    int row = o >> 7, col = o & 127;
    *(int4*)(Hq + (size_t)(bM + row) * I + bN + col) = *(const int4*)(sH + o);
  }
}

// ---------------- GEMM2: dual B-panel (TN=256) + B-dbuf counted vmcnt ----------------
__global__ __launch_bounds__(256, 2) void gemm2_down(
    const uint8_t* __restrict__ Hq,   // [M][I]
    const uint8_t* __restrict__ Dq,   // [Hd][I]
    float* __restrict__ Out,          // [M][Hd]
    const float* __restrict__ dws, const float* __restrict__ dis,
    int M, int I, int Hd) {
  __shared__ uint8_t sA[TM * BKB];          // 16KB, single-buffered
  __shared__ uint8_t sB[2][2 * TN * BKB];   // 2 x 32KB -> 80KB total

  const int tid = threadIdx.x;
  const int wave = tid >> 6, lane = tid & 63;
  const int wr = wave >> 1, wc = wave & 1;   // wave-tile: 64 rows x 128 cols
  const int lrow = lane & 15;
  const int lkg = lane >> 4;
  const int swz = (lrow & 7) << 4;
  const int ko = lkg * 32;

  // 2D supertile (R15): GX=16 covers ALL x-panels, GY=16 -> 256-block groups.
  const int g = blockIdx.x >> 8, w = blockIdx.x & 255;   // 4 groups
  const int xb = w >> 4;
  const int yb = (g << 4) + (w & 15);
  const int bM = yb * TM, bN = xb * 256;

  f32x4 acc[4][8] = {};

  const uint8_t* ga = Hq + (size_t)bM * I;
  const uint8_t* gb = Dq + (size_t)bN * I;

  auto stageA = [&](int k0) {                // 4 issues/thread
#pragma unroll
    for (int it = 0; it < 4; ++it) {
      int c = it * 256 + tid;
      int r = c >> 3;
      int col = ((c & 7) ^ (r & 7)) * 16;
      gld_lds16(ga + (size_t)r * I + k0 + col, sA + (it * 4 + wave) * 1024);
    }
  };
  auto stageB = [&](int buf, int k0) {       // 8 issues/thread
#pragma unroll
    for (int it = 0; it < 8; ++it) {
      int c = it * 256 + tid;
      int r = c >> 3;                        // 0..255
      int col = ((c & 7) ^ (r & 7)) * 16;
      gld_lds16(gb + (size_t)r * I + k0 + col, &sB[buf][(it * 4 + wave) * 1024]);
    }
  };

  const int NK = I / BKB;                    // 86
  stageB(0, 0);

  for (int t = 0; t < NK; ++t) {
    const int cur = t & 1, nxt = cur ^ 1;
    stageA(t * BKB);
    if (t + 1 < NK) {
      stageB(nxt, (t + 1) * BKB);
      asm volatile("s_waitcnt vmcnt(8)" ::: "memory");  // A(t)+B(t) arrived
    } else {
      asm volatile("s_waitcnt vmcnt(0)" ::: "memory");
    }
    __builtin_amdgcn_s_barrier();

    i32x8 af[4];
#pragma unroll
    for (int i = 0; i < 4; ++i)
      af[i] = read_frag32(sA, wr * 64 + i * 16 + lrow, ko, swz);
#pragma unroll
    for (int j = 0; j < 8; ++j) {
      i32x8 bf = read_frag32(&sB[cur][0], wc * 128 + j * 16 + lrow, ko, swz);
#pragma unroll
      for (int i = 0; i < 4; ++i)
        acc[i][j] = __builtin_amdgcn_mfma_scale_f32_16x16x128_f8f6f4(
            af[i], bf, acc[i][j], 0, 0, 0, SCALE1, 0, SCALE1);
    }
    asm volatile("s_waitcnt lgkmcnt(0)" ::: "memory");
    __builtin_amdgcn_s_barrier();
  }

  const float ds = dws[0] * dis[0];
#pragma unroll
  for (int i = 0; i < 4; ++i)
#pragma unroll
    for (int j = 0; j < 8; ++j) {
      int row = bM + wr * 64 + i * 16 + lkg * 4;
      int col = bN + wc * 128 + j * 16 + lrow;
#pragma unroll
      for (int t = 0; t < 4; ++t)
        Out[(size_t)(row + t) * Hd + col] = acc[i][j][t] * ds;
    }
}

extern "C" void kernel_launch(void* const* d_in, const int* in_sizes, int n_in,
                              void* d_out, int out_size, void* d_ws, size_t ws_size,
                              hipStream_t stream) {
  const float* x   = (const float*)d_in[0];
  const float* gw  = (const float*)d_in[1];
  const float* uw  = (const float*)d_in[2];
  const float* dw  = (const float*)d_in[3];
  const float* gws = (const float*)d_in[4];
  const float* uws = (const float*)d_in[5];
  const float* dws = (const float*)d_in[6];
  const float* gis = (const float*)d_in[7];
  const float* uis = (const float*)d_in[8];
  const float* dis = (const float*)d_in[9];

  const int Hd = 4096;
  const int M  = in_sizes[0] / Hd;          // 8192
  const int I  = in_sizes[1] / Hd;          // 11008

  const size_t szX = (size_t)M * Hd;        // 33.5 MB
  const size_t szW = (size_t)I * Hd;        // 45.1 MB
  const size_t szH = (size_t)M * I;         // 90.2 MB

  uint8_t* xq = (uint8_t*)d_ws;
  uint8_t* gq = xq + szX;
  uint8_t* uq = gq + szW;
  uint8_t* hq = uq + szW;
  uint8_t* dq = gq;                         // reuse gate slot after GEMM1

  if (ws_size < szX + 2 * szW + szH) return;  // fail loudly (out stays poisoned)

  float* out = (float*)d_out;

  // 1. quantize activations and GEMM1 weights
  {
    long n8 = (long)(szX / 8);
    quant_fp8_k<<<dim3((n8 + 255) / 256), dim3(256), 0, stream>>>(x, xq, gis, n8);
  }
  {
    long n8 = (long)(szW / 8);
    quant_fp8_k<<<dim3((n8 + 255) / 256), dim3(256), 0, stream>>>(gw, gq, nullptr, n8);
    quant_fp8_k<<<dim3((n8 + 255) / 256), dim3(256), 0, stream>>>(uw, uq, nullptr, n8);
  }

  // 2. fused gate/up GEMM + SwiGLU + fp8 requant of hidden
  gemm1_swiglu<<<dim3((I / TN) * (M / TM)), dim3(256), 0, stream>>>(
      xq, gq, uq, hq, gws, uws, gis, uis, dis, M, Hd, I);

  // 3. quantize down weights (into gate slot), then down GEMM
  {
    long n8 = (long)(szW / 8);
    quant_fp8_k<<<dim3((n8 + 255) / 256), dim3(256), 0, stream>>>(dw, dq, nullptr, n8);
  }
  gemm2_down<<<dim3((Hd / 256) * (M / TM)), dim3(256), 0, stream>>>(
      hq, dq, out, dws, dis, M, I, Hd);
}